// Round 4
// baseline (1273.009 us; speedup 1.0000x reference)
//
#include <hip/hip_runtime.h>

#define KK 27
#define CC 64
#define EPS 1e-5f

typedef float    f32x4 __attribute__((ext_vector_type(4)));
typedef unsigned u32x4 __attribute__((ext_vector_type(4)));

// ---------------------------------------------------------------------------
// Pack two fp32 -> bf16x2 (round-to-nearest-even)
// ---------------------------------------------------------------------------
__device__ __forceinline__ unsigned pack_bf16x2(float a, float b) {
    unsigned ua = __float_as_uint(a);
    unsigned ub = __float_as_uint(b);
    ua = (ua + 0x7fffu + ((ua >> 16) & 1u)) >> 16;
    ub = (ub + 0x7fffu + ((ub >> 16) & 1u)) >> 16;
    return ua | (ub << 16);
}

// ---------------------------------------------------------------------------
// Kernel 0: fp32 data [N][64] -> packed bf16 [N][64] (128 MB, L3-resident).
// ---------------------------------------------------------------------------
__global__ __launch_bounds__(256, 8) void convert_kernel(
    const f32x4* __restrict__ d4, u32x4* __restrict__ o4, long n_out)
{
    const long stride = (long)gridDim.x * 256;
    for (long i = (long)blockIdx.x * 256 + threadIdx.x; i < n_out; i += stride) {
        f32x4 a = __builtin_nontemporal_load(&d4[2 * i]);
        f32x4 b = __builtin_nontemporal_load(&d4[2 * i + 1]);
        u32x4 o;
        o.x = pack_bf16x2(a.x, a.y);
        o.y = pack_bf16x2(a.z, a.w);
        o.z = pack_bf16x2(b.x, b.y);
        o.w = pack_bf16x2(b.z, b.w);
        o4[i] = o;
    }
}

// ---------------------------------------------------------------------------
// Kernel 1: gather-conv + per-channel partial sums.
// 8 lanes per row (lane = 8 channels = one u32x4 = 16B), 32 rows per block
// iteration. Indices staged through LDS. 8 waves/EU for gather MLP.
// BF16_OUT: write packed-bf16 intermediate (to ws) instead of fp32.
// ---------------------------------------------------------------------------
template <bool BF16_OUT>
__global__ __launch_bounds__(256, 8) void conv_bf16_kernel(
    const u32x4* __restrict__ dbf,      // [N][8] u32x4 rows (packed bf16)
    const float* __restrict__ weights,  // [27][64] fp32
    const int*   __restrict__ neigh,    // [N][27]
    float* __restrict__ outf,           // [N][64] fp32 (if !BF16_OUT)
    u32x4* __restrict__ outb,           // [N][8]  bf16 (if BF16_OUT)
    float* __restrict__ gsum,
    float* __restrict__ gsq,
    int N)
{
    __shared__ float s_w[KK * CC];       // 6912 B
    __shared__ int   s_idx[32 * 28];     // 3584 B
    __shared__ float s_red[256 * 8];     // 8192 B

    const int tid = threadIdx.x;
    for (int i = tid; i < KK * CC / 4; i += 256)
        ((f32x4*)s_w)[i] = ((const f32x4*)weights)[i];

    const int lane = tid & 7;   // channels lane*8 .. lane*8+7
    const int r    = tid >> 3;  // row within block-iteration (0..31)

    float lsum[8], lsq[8];
    #pragma unroll
    for (int j = 0; j < 8; ++j) { lsum[j] = 0.f; lsq[j] = 0.f; }

    const long rows_per_iter = (long)gridDim.x * 32;
    for (long base = (long)blockIdx.x * 32; base < N; base += rows_per_iter) {
        __syncthreads();
        {
            const int nrows = (int)min((long)32, (long)N - base);
            const int tot = nrows * KK;
            for (int i = tid; i < tot; i += 256) {
                const int rr = i / KK;
                const int kk = i - rr * KK;
                s_idx[rr * 28 + kk] =
                    __builtin_nontemporal_load(&neigh[(base + rr) * KK + kk]);
            }
        }
        __syncthreads();

        const long row = base + r;
        if (row < N) {
            float acc[8];
            #pragma unroll
            for (int j = 0; j < 8; ++j) acc[j] = 0.f;

            const int4* nb4 = (const int4*)&s_idx[r * 28];

            auto process = [&](int idx, int k) {
                const unsigned msk = (idx >= 0) ? 0xffffffffu : 0u;
                const long ci = (idx >= 0) ? (long)idx : 0L;
                u32x4 g = dbf[ci * 8 + lane];
                g.x &= msk; g.y &= msk; g.z &= msk; g.w &= msk;
                const f32x4 w0 = *(const f32x4*)&s_w[k * CC + lane * 8];
                const f32x4 w1 = *(const f32x4*)&s_w[k * CC + lane * 8 + 4];
                acc[0] = fmaf(__uint_as_float(g.x << 16),         w0.x, acc[0]);
                acc[1] = fmaf(__uint_as_float(g.x & 0xffff0000u), w0.y, acc[1]);
                acc[2] = fmaf(__uint_as_float(g.y << 16),         w0.z, acc[2]);
                acc[3] = fmaf(__uint_as_float(g.y & 0xffff0000u), w0.w, acc[3]);
                acc[4] = fmaf(__uint_as_float(g.z << 16),         w1.x, acc[4]);
                acc[5] = fmaf(__uint_as_float(g.z & 0xffff0000u), w1.y, acc[5]);
                acc[6] = fmaf(__uint_as_float(g.w << 16),         w1.z, acc[6]);
                acc[7] = fmaf(__uint_as_float(g.w & 0xffff0000u), w1.w, acc[7]);
            };

            #pragma unroll
            for (int kk = 0; kk < 7; ++kk) {
                const int4 q = nb4[kk];
                const int kb = kk * 4;
                process(q.x, kb + 0);
                process(q.y, kb + 1);
                process(q.z, kb + 2);
                if (kb + 3 < KK) process(q.w, kb + 3);
            }

            if (BF16_OUT) {
                u32x4 o;
                o.x = pack_bf16x2(acc[0], acc[1]);
                o.y = pack_bf16x2(acc[2], acc[3]);
                o.z = pack_bf16x2(acc[4], acc[5]);
                o.w = pack_bf16x2(acc[6], acc[7]);
                __builtin_nontemporal_store(o, &outb[row * 8 + lane]);
            } else {
                f32x4 v0 = {acc[0], acc[1], acc[2], acc[3]};
                f32x4 v1 = {acc[4], acc[5], acc[6], acc[7]};
                f32x4* op = (f32x4*)&outf[row * CC + lane * 8];
                __builtin_nontemporal_store(v0, &op[0]);
                __builtin_nontemporal_store(v1, &op[1]);
            }

            #pragma unroll
            for (int j = 0; j < 8; ++j) {
                lsum[j] += acc[j];
                lsq[j]  += acc[j] * acc[j];
            }
        }
    }

    __syncthreads();
    #pragma unroll
    for (int j = 0; j < 8; ++j) s_red[tid * 8 + j] = lsum[j];
    __syncthreads();
    if (tid < CC) {
        const int blk = tid >> 3, off = tid & 7;
        float s = 0.f;
        for (int rr = 0; rr < 32; ++rr) s += s_red[(rr * 8 + blk) * 8 + off];
        atomicAdd(&gsum[tid], s);
    }
    __syncthreads();
    #pragma unroll
    for (int j = 0; j < 8; ++j) s_red[tid * 8 + j] = lsq[j];
    __syncthreads();
    if (tid < CC) {
        const int blk = tid >> 3, off = tid & 7;
        float s = 0.f;
        for (int rr = 0; rr < 32; ++rr) s += s_red[(rr * 8 + blk) * 8 + off];
        atomicAdd(&gsq[tid], s);
    }
}

// ---------------------------------------------------------------------------
// Fallback fp32 conv (only if ws too small for the bf16 data copy).
// ---------------------------------------------------------------------------
__global__ __launch_bounds__(256, 8) void conv_fp32_kernel(
    const float* __restrict__ data,
    const float* __restrict__ weights,
    const int*   __restrict__ neigh,
    float* __restrict__ out,
    float* __restrict__ gsum,
    float* __restrict__ gsq,
    int N)
{
    __shared__ f32x4 s_w[KK * 16];
    __shared__ f32x4 s_red[256];

    const int tid = threadIdx.x;
    for (int i = tid; i < KK * 16; i += 256)
        s_w[i] = reinterpret_cast<const f32x4*>(weights)[i];
    __syncthreads();

    const int cq = tid & 15;
    const int rg = tid >> 4;
    const f32x4* data4 = reinterpret_cast<const f32x4*>(data);
    f32x4* out4 = reinterpret_cast<f32x4*>(out);

    f32x4 lsum = {0.f, 0.f, 0.f, 0.f};
    f32x4 lsq  = {0.f, 0.f, 0.f, 0.f};

    const long rows_per_iter = (long)gridDim.x * 16;
    for (long base = (long)blockIdx.x * 16; base < N; base += rows_per_iter) {
        const long row = base + rg;
        if (row < N) {
            f32x4 acc = {0.f, 0.f, 0.f, 0.f};
            const int* nb = neigh + row * KK;
            #pragma unroll
            for (int k = 0; k < KK; ++k) {
                const int idx = nb[k];
                if (idx >= 0) {
                    const f32x4 g = data4[(long)idx * 16 + cq];
                    const f32x4 w = s_w[k * 16 + cq];
                    acc += g * w;
                }
            }
            out4[row * 16 + cq] = acc;
            lsum += acc;
            lsq  += acc * acc;
        }
    }

    s_red[tid] = lsum;
    __syncthreads();
    if (rg == 0) {
        f32x4 t = s_red[cq];
        #pragma unroll
        for (int r = 1; r < 16; ++r) t += s_red[r * 16 + cq];
        atomicAdd(&gsum[cq * 4 + 0], t.x);
        atomicAdd(&gsum[cq * 4 + 1], t.y);
        atomicAdd(&gsum[cq * 4 + 2], t.z);
        atomicAdd(&gsum[cq * 4 + 3], t.w);
    }
    __syncthreads();
    s_red[tid] = lsq;
    __syncthreads();
    if (rg == 0) {
        f32x4 t = s_red[cq];
        #pragma unroll
        for (int r = 1; r < 16; ++r) t += s_red[r * 16 + cq];
        atomicAdd(&gsq[cq * 4 + 0], t.x);
        atomicAdd(&gsq[cq * 4 + 1], t.y);
        atomicAdd(&gsq[cq * 4 + 2], t.z);
        atomicAdd(&gsq[cq * 4 + 3], t.w);
    }
}

// ---------------------------------------------------------------------------
// Kernel 2: fold sums into per-channel scale/bias
// ---------------------------------------------------------------------------
__global__ void stats_kernel(const float* __restrict__ gsum,
                             const float* __restrict__ gsq,
                             const float* __restrict__ gamma,
                             const float* __restrict__ beta,
                             float* __restrict__ scale,
                             float* __restrict__ bias,
                             int N)
{
    const int c = threadIdx.x;
    if (c < CC) {
        const float inv_n = 1.0f / (float)N;
        const float mean = gsum[c] * inv_n;
        float var = gsq[c] * inv_n - mean * mean;
        var = fmaxf(var, 0.0f);
        const float s = gamma[c] * rsqrtf(var + EPS);
        scale[c] = s;
        bias[c] = beta[c] - mean * s;
    }
}

// ---------------------------------------------------------------------------
// Kernel 3a: in-place normalize fp32 out (fallback path)
// ---------------------------------------------------------------------------
__global__ __launch_bounds__(256, 8) void norm_kernel(
    float* __restrict__ out,
    const float* __restrict__ scale,
    const float* __restrict__ bias,
    long total4)
{
    const long i0 = (long)blockIdx.x * 256 + threadIdx.x;
    const int cq = (int)(i0 & 15);
    const f32x4 s = reinterpret_cast<const f32x4*>(scale)[cq];
    const f32x4 b = reinterpret_cast<const f32x4*>(bias)[cq];
    f32x4* o4 = reinterpret_cast<f32x4*>(out);
    const long stride = (long)gridDim.x * 256;
    for (long i = i0; i < total4; i += stride) {
        f32x4 v = __builtin_nontemporal_load(&o4[i]);
        v = v * s + b;
        __builtin_nontemporal_store(v, &o4[i]);
    }
}

// ---------------------------------------------------------------------------
// Kernel 3b: normalize from bf16 intermediate -> fp32 d_out.
// Thread handles one u32x4 (8 channels). lane = i & 7.
// ---------------------------------------------------------------------------
__global__ __launch_bounds__(256, 8) void norm_bf16_kernel(
    const u32x4* __restrict__ inb,      // [N][8]
    float* __restrict__ out,            // [N][64]
    const float* __restrict__ scale,
    const float* __restrict__ bias,
    long total8)                        // N * 8
{
    const long i0 = (long)blockIdx.x * 256 + threadIdx.x;
    const int lane = (int)(i0 & 7);
    const f32x4 s0 = reinterpret_cast<const f32x4*>(scale)[lane * 2];
    const f32x4 s1 = reinterpret_cast<const f32x4*>(scale)[lane * 2 + 1];
    const f32x4 b0 = reinterpret_cast<const f32x4*>(bias)[lane * 2];
    const f32x4 b1 = reinterpret_cast<const f32x4*>(bias)[lane * 2 + 1];
    const long stride = (long)gridDim.x * 256;   // multiple of 8
    for (long i = i0; i < total8; i += stride) {
        u32x4 g = __builtin_nontemporal_load(&inb[i]);
        f32x4 v0, v1;
        v0.x = __uint_as_float(g.x << 16);
        v0.y = __uint_as_float(g.x & 0xffff0000u);
        v0.z = __uint_as_float(g.y << 16);
        v0.w = __uint_as_float(g.y & 0xffff0000u);
        v1.x = __uint_as_float(g.z << 16);
        v1.y = __uint_as_float(g.z & 0xffff0000u);
        v1.z = __uint_as_float(g.w << 16);
        v1.w = __uint_as_float(g.w & 0xffff0000u);
        v0 = v0 * s0 + b0;
        v1 = v1 * s1 + b1;
        f32x4* op = (f32x4*)&out[i * 8];
        __builtin_nontemporal_store(v0, &op[0]);
        __builtin_nontemporal_store(v1, &op[1]);
    }
}

extern "C" void kernel_launch(void* const* d_in, const int* in_sizes, int n_in,
                              void* d_out, int out_size, void* d_ws, size_t ws_size,
                              hipStream_t stream)
{
    const float* data    = (const float*)d_in[0];
    const float* weights = (const float*)d_in[1];
    const float* gamma   = (const float*)d_in[2];
    const float* beta    = (const float*)d_in[3];
    const int*   neigh   = (const int*)d_in[4];
    float* out = (float*)d_out;
    const int N = in_sizes[0] / CC;     // 1,000,000

    float* gsum  = (float*)d_ws;        // [64]
    float* gsq   = gsum + CC;           // [64]
    float* scale = gsq + CC;            // [64]
    float* bias  = scale + CC;          // [64]

    (void)hipMemsetAsync(d_ws, 0, 2 * CC * sizeof(float), stream);

    const size_t bf16_bytes = (size_t)N * CC * 2;   // 128 MB
    const size_t off1 = 1024;                        // data bf16 copy
    const size_t off2 = off1 + bf16_bytes;           // conv bf16 intermediate

    if (ws_size >= off1 + bf16_bytes) {
        u32x4* dbf = (u32x4*)((char*)d_ws + off1);
        const long n_out = (long)N * CC / 8;
        convert_kernel<<<2048, 256, 0, stream>>>(
            (const f32x4*)data, dbf, n_out);

        const bool bf16_out = (ws_size >= off2 + bf16_bytes);
        if (bf16_out) {
            u32x4* cbf = (u32x4*)((char*)d_ws + off2);
            conv_bf16_kernel<true><<<2048, 256, 0, stream>>>(
                dbf, weights, neigh, nullptr, cbf, gsum, gsq, N);
            stats_kernel<<<1, 64, 0, stream>>>(gsum, gsq, gamma, beta,
                                               scale, bias, N);
            norm_bf16_kernel<<<2048, 256, 0, stream>>>(
                cbf, out, scale, bias, (long)N * 8);
        } else {
            conv_bf16_kernel<false><<<2048, 256, 0, stream>>>(
                dbf, weights, neigh, out, nullptr, gsum, gsq, N);
            stats_kernel<<<1, 64, 0, stream>>>(gsum, gsq, gamma, beta,
                                               scale, bias, N);
            norm_kernel<<<2048, 256, 0, stream>>>(
                out, scale, bias, (long)N * (CC / 4));
        }
    } else {
        conv_fp32_kernel<<<2048, 256, 0, stream>>>(
            data, weights, neigh, out, gsum, gsq, N);
        stats_kernel<<<1, 64, 0, stream>>>(gsum, gsq, gamma, beta,
                                           scale, bias, N);
        norm_kernel<<<2048, 256, 0, stream>>>(
            out, scale, bias, (long)N * (CC / 4));
    }
}

// Round 5
// 1133.491 us; speedup vs baseline: 1.1231x; 1.1231x over previous
//
#include <hip/hip_runtime.h>
#include <type_traits>

#define KK 27
#define CC 64
#define EPS 1e-5f

typedef float    f32x4 __attribute__((ext_vector_type(4)));
typedef unsigned u32x4 __attribute__((ext_vector_type(4)));

// ---------------------------------------------------------------------------
// Pack two fp32 -> bf16x2 (round-to-nearest-even)
// ---------------------------------------------------------------------------
__device__ __forceinline__ unsigned pack_bf16x2(float a, float b) {
    unsigned ua = __float_as_uint(a);
    unsigned ub = __float_as_uint(b);
    ua = (ua + 0x7fffu + ((ua >> 16) & 1u)) >> 16;
    ub = (ub + 0x7fffu + ((ub >> 16) & 1u)) >> 16;
    return ua | (ub << 16);
}

// ---------------------------------------------------------------------------
// Kernel 0 (split path): fp32 [N][64] -> two bf16 planes [(N+1)][32].
// Plane A = channels 0..31, plane B = channels 32..63 (64 MB each).
// ---------------------------------------------------------------------------
__global__ __launch_bounds__(256, 8) void convert_split_kernel(
    const f32x4* __restrict__ d4, u32x4* __restrict__ pA,
    u32x4* __restrict__ pB, long total8)          // total8 = N*8
{
    const long stride = (long)gridDim.x * 256;
    for (long i = (long)blockIdx.x * 256 + threadIdx.x; i < total8; i += stride) {
        f32x4 a = __builtin_nontemporal_load(&d4[2 * i]);
        f32x4 b = __builtin_nontemporal_load(&d4[2 * i + 1]);
        u32x4 o;
        o.x = pack_bf16x2(a.x, a.y);
        o.y = pack_bf16x2(a.z, a.w);
        o.z = pack_bf16x2(b.x, b.y);
        o.w = pack_bf16x2(b.z, b.w);
        const long row = i >> 3;
        const int  o8  = (int)(i & 7);
        u32x4* dst = (o8 < 4) ? pA : pB;
        dst[row * 4 + (o8 & 3)] = o;
    }
}

// ---------------------------------------------------------------------------
// Kernel 1 (split path): gather-conv over ONE 64 MB plane (32 channels).
// 4 lanes per row (lane = 8 ch = one u32x4 = 16B), 64 rows per block iter.
// Explicit 9-deep gather batches in registers. Invalid idx -> dummy row N
// (zeroed) so no masking is needed. launch_bounds(256,4): ~75 VGPR, no spill.
// ---------------------------------------------------------------------------
__global__ __launch_bounds__(256, 4) void conv_half_kernel(
    const u32x4* __restrict__ plane,    // [(N+1)][4] u32x4 (bf16)
    const float* __restrict__ weights,  // [27][64] fp32, cols [coff,coff+32)
    const int*   __restrict__ neigh,    // [N][27]
    u32x4* __restrict__ outp,           // [N][4] bf16 conv output half
    float* __restrict__ gsum,
    float* __restrict__ gsq,
    int N, int coff)
{
    __shared__ float s_w[KK * 32];       // 3456 B
    __shared__ int   s_idx[64 * 28];     // 7168 B
    __shared__ float s_red[256 * 8];     // 8192 B

    const int tid = threadIdx.x;
    // s_w[k*32 + c] = weights[k*64 + coff + c]
    for (int i = tid; i < KK * 8; i += 256) {
        const int k = i >> 3, j = i & 7;
        ((f32x4*)s_w)[k * 8 + j] =
            ((const f32x4*)weights)[k * 16 + (coff >> 2) + j];
    }

    const int lane = tid & 3;   // channels coff+lane*8 .. +8
    const int r    = tid >> 2;  // row within block-iteration (0..63)

    float lsum[8], lsq[8];
    #pragma unroll
    for (int j = 0; j < 8; ++j) { lsum[j] = 0.f; lsq[j] = 0.f; }

    const long rows_per_iter = (long)gridDim.x * 64;
    for (long base = (long)blockIdx.x * 64; base < N; base += rows_per_iter) {
        __syncthreads();
        {
            const int nrows = (int)min((long)64, (long)N - base);
            const int tot = nrows * KK;
            for (int i = tid; i < tot; i += 256) {
                const int rr = i / KK;
                const int kk = i - rr * KK;
                s_idx[rr * 28 + kk] =
                    __builtin_nontemporal_load(&neigh[(base + rr) * KK + kk]);
            }
        }
        __syncthreads();

        const long row = base + r;
        if (row < N) {
            float acc[8];
            #pragma unroll
            for (int j = 0; j < 8; ++j) acc[j] = 0.f;

            auto do_batch = [&](auto KBc, int k0) {
                constexpr int KB = decltype(KBc)::value;
                u32x4 g[KB];
                #pragma unroll
                for (int j = 0; j < KB; ++j) {
                    const int idx = s_idx[r * 28 + k0 + j];
                    const long ci = (idx >= 0) ? (long)idx : (long)N;
                    g[j] = plane[ci * 4 + lane];
                }
                #pragma unroll
                for (int j = 0; j < KB; ++j) {
                    const int k = k0 + j;
                    const f32x4 w0 = *(const f32x4*)&s_w[k * 32 + lane * 8];
                    const f32x4 w1 = *(const f32x4*)&s_w[k * 32 + lane * 8 + 4];
                    acc[0] = fmaf(__uint_as_float(g[j].x << 16),         w0.x, acc[0]);
                    acc[1] = fmaf(__uint_as_float(g[j].x & 0xffff0000u), w0.y, acc[1]);
                    acc[2] = fmaf(__uint_as_float(g[j].y << 16),         w0.z, acc[2]);
                    acc[3] = fmaf(__uint_as_float(g[j].y & 0xffff0000u), w0.w, acc[3]);
                    acc[4] = fmaf(__uint_as_float(g[j].z << 16),         w1.x, acc[4]);
                    acc[5] = fmaf(__uint_as_float(g[j].z & 0xffff0000u), w1.y, acc[5]);
                    acc[6] = fmaf(__uint_as_float(g[j].w << 16),         w1.z, acc[6]);
                    acc[7] = fmaf(__uint_as_float(g[j].w & 0xffff0000u), w1.w, acc[7]);
                }
            };
            do_batch(std::integral_constant<int, 9>{}, 0);
            do_batch(std::integral_constant<int, 9>{}, 9);
            do_batch(std::integral_constant<int, 9>{}, 18);

            u32x4 o;
            o.x = pack_bf16x2(acc[0], acc[1]);
            o.y = pack_bf16x2(acc[2], acc[3]);
            o.z = pack_bf16x2(acc[4], acc[5]);
            o.w = pack_bf16x2(acc[6], acc[7]);
            __builtin_nontemporal_store(o, &outp[row * 4 + lane]);

            #pragma unroll
            for (int j = 0; j < 8; ++j) {
                lsum[j] += acc[j];
                lsq[j]  += acc[j] * acc[j];
            }
        }
    }

    // Block reduction over the 64 row-groups; 32 channels this pass.
    __syncthreads();
    #pragma unroll
    for (int j = 0; j < 8; ++j) s_red[tid * 8 + j] = lsum[j];
    __syncthreads();
    if (tid < 32) {
        const int blk = tid >> 3, off = tid & 7;
        float s = 0.f;
        for (int rr = 0; rr < 64; ++rr) s += s_red[(rr * 4 + blk) * 8 + off];
        atomicAdd(&gsum[coff + tid], s);
    }
    __syncthreads();
    #pragma unroll
    for (int j = 0; j < 8; ++j) s_red[tid * 8 + j] = lsq[j];
    __syncthreads();
    if (tid < 32) {
        const int blk = tid >> 3, off = tid & 7;
        float s = 0.f;
        for (int rr = 0; rr < 64; ++rr) s += s_red[(rr * 4 + blk) * 8 + off];
        atomicAdd(&gsq[coff + tid], s);
    }
}

// ---------------------------------------------------------------------------
// Kernel 3 (split path): normalize from two bf16 planes -> fp32 d_out.
// ---------------------------------------------------------------------------
__global__ __launch_bounds__(256, 8) void norm_split_kernel(
    const u32x4* __restrict__ pA, const u32x4* __restrict__ pB,
    float* __restrict__ out,
    const float* __restrict__ scale, const float* __restrict__ bias,
    long total8)                        // N * 8
{
    const long i0 = (long)blockIdx.x * 256 + threadIdx.x;
    const int lane = (int)(i0 & 7);     // loop-invariant (stride % 8 == 0)
    const f32x4 s0 = reinterpret_cast<const f32x4*>(scale)[lane * 2];
    const f32x4 s1 = reinterpret_cast<const f32x4*>(scale)[lane * 2 + 1];
    const f32x4 b0 = reinterpret_cast<const f32x4*>(bias)[lane * 2];
    const f32x4 b1 = reinterpret_cast<const f32x4*>(bias)[lane * 2 + 1];
    const u32x4* __restrict__ src = (lane < 4) ? pA : pB;
    const int l4 = lane & 3;
    const long stride = (long)gridDim.x * 256;
    for (long i = i0; i < total8; i += stride) {
        const long row = i >> 3;
        u32x4 g = __builtin_nontemporal_load(&src[row * 4 + l4]);
        f32x4 v0, v1;
        v0.x = __uint_as_float(g.x << 16);
        v0.y = __uint_as_float(g.x & 0xffff0000u);
        v0.z = __uint_as_float(g.y << 16);
        v0.w = __uint_as_float(g.y & 0xffff0000u);
        v1.x = __uint_as_float(g.z << 16);
        v1.y = __uint_as_float(g.z & 0xffff0000u);
        v1.z = __uint_as_float(g.w << 16);
        v1.w = __uint_as_float(g.w & 0xffff0000u);
        v0 = v0 * s0 + b0;
        v1 = v1 * s1 + b1;
        f32x4* op = (f32x4*)&out[i * 8];
        __builtin_nontemporal_store(v0, &op[0]);
        __builtin_nontemporal_store(v1, &op[1]);
    }
}

// ---------------------------------------------------------------------------
// Kernel 2: fold sums into per-channel scale/bias
// ---------------------------------------------------------------------------
__global__ void stats_kernel(const float* __restrict__ gsum,
                             const float* __restrict__ gsq,
                             const float* __restrict__ gamma,
                             const float* __restrict__ beta,
                             float* __restrict__ scale,
                             float* __restrict__ bias,
                             int N)
{
    const int c = threadIdx.x;
    if (c < CC) {
        const float inv_n = 1.0f / (float)N;
        const float mean = gsum[c] * inv_n;
        float var = gsq[c] * inv_n - mean * mean;
        var = fmaxf(var, 0.0f);
        const float s = gamma[c] * rsqrtf(var + EPS);
        scale[c] = s;
        bias[c] = beta[c] - mean * s;
    }
}

// ---------------------------------------------------------------------------
// Fallback tier: fp32 conv (ws too small for any bf16 copy).
// ---------------------------------------------------------------------------
__global__ __launch_bounds__(256, 4) void conv_fp32_kernel(
    const float* __restrict__ data,
    const float* __restrict__ weights,
    const int*   __restrict__ neigh,
    float* __restrict__ out,
    float* __restrict__ gsum,
    float* __restrict__ gsq,
    int N)
{
    __shared__ f32x4 s_w[KK * 16];
    __shared__ f32x4 s_red[256];

    const int tid = threadIdx.x;
    for (int i = tid; i < KK * 16; i += 256)
        s_w[i] = reinterpret_cast<const f32x4*>(weights)[i];
    __syncthreads();

    const int cq = tid & 15;
    const int rg = tid >> 4;
    const f32x4* data4 = reinterpret_cast<const f32x4*>(data);
    f32x4* out4 = reinterpret_cast<f32x4*>(out);

    f32x4 lsum = {0.f, 0.f, 0.f, 0.f};
    f32x4 lsq  = {0.f, 0.f, 0.f, 0.f};

    const long rows_per_iter = (long)gridDim.x * 16;
    for (long base = (long)blockIdx.x * 16; base < N; base += rows_per_iter) {
        const long row = base + rg;
        if (row < N) {
            f32x4 acc = {0.f, 0.f, 0.f, 0.f};
            const int* nb = neigh + row * KK;
            #pragma unroll
            for (int k = 0; k < KK; ++k) {
                const int idx = nb[k];
                if (idx >= 0) {
                    const f32x4 g = data4[(long)idx * 16 + cq];
                    const f32x4 w = s_w[k * 16 + cq];
                    acc += g * w;
                }
            }
            out4[row * 16 + cq] = acc;
            lsum += acc;
            lsq  += acc * acc;
        }
    }

    s_red[tid] = lsum;
    __syncthreads();
    if (rg == 0) {
        f32x4 t = s_red[cq];
        #pragma unroll
        for (int r = 1; r < 16; ++r) t += s_red[r * 16 + cq];
        atomicAdd(&gsum[cq * 4 + 0], t.x);
        atomicAdd(&gsum[cq * 4 + 1], t.y);
        atomicAdd(&gsum[cq * 4 + 2], t.z);
        atomicAdd(&gsum[cq * 4 + 3], t.w);
    }
    __syncthreads();
    s_red[tid] = lsq;
    __syncthreads();
    if (rg == 0) {
        f32x4 t = s_red[cq];
        #pragma unroll
        for (int r = 1; r < 16; ++r) t += s_red[r * 16 + cq];
        atomicAdd(&gsq[cq * 4 + 0], t.x);
        atomicAdd(&gsq[cq * 4 + 1], t.y);
        atomicAdd(&gsq[cq * 4 + 2], t.z);
        atomicAdd(&gsq[cq * 4 + 3], t.w);
    }
}

__global__ __launch_bounds__(256, 8) void norm_kernel(
    float* __restrict__ out,
    const float* __restrict__ scale,
    const float* __restrict__ bias,
    long total4)
{
    const long i0 = (long)blockIdx.x * 256 + threadIdx.x;
    const int cq = (int)(i0 & 15);
    const f32x4 s = reinterpret_cast<const f32x4*>(scale)[cq];
    const f32x4 b = reinterpret_cast<const f32x4*>(bias)[cq];
    f32x4* o4 = reinterpret_cast<f32x4*>(out);
    const long stride = (long)gridDim.x * 256;
    for (long i = i0; i < total4; i += stride) {
        f32x4 v = __builtin_nontemporal_load(&o4[i]);
        v = v * s + b;
        __builtin_nontemporal_store(v, &o4[i]);
    }
}

extern "C" void kernel_launch(void* const* d_in, const int* in_sizes, int n_in,
                              void* d_out, int out_size, void* d_ws, size_t ws_size,
                              hipStream_t stream)
{
    const float* data    = (const float*)d_in[0];
    const float* weights = (const float*)d_in[1];
    const float* gamma   = (const float*)d_in[2];
    const float* beta    = (const float*)d_in[3];
    const int*   neigh   = (const int*)d_in[4];
    float* out = (float*)d_out;
    const int N = in_sizes[0] / CC;     // 1,000,000

    float* gsum  = (float*)d_ws;        // [64]
    float* gsq   = gsum + CC;           // [64]
    float* scale = gsq + CC;            // [64]
    float* bias  = scale + CC;          // [64]

    (void)hipMemsetAsync(d_ws, 0, 2 * CC * sizeof(float), stream);

    const size_t off0    = 1024;
    const size_t planeSz = (size_t)(N + 1) * 32 * 2;   // ~64 MB (+dummy row)
    const size_t halfSz  = (size_t)N * 32 * 2;         // 64 MB

    if (ws_size >= off0 + 2 * planeSz + 2 * halfSz) {
        // --- split path ---
        char* base = (char*)d_ws;
        u32x4* pA   = (u32x4*)(base + off0);
        u32x4* pB   = (u32x4*)(base + off0 + planeSz);
        u32x4* outA = (u32x4*)(base + off0 + 2 * planeSz);
        u32x4* outB = (u32x4*)(base + off0 + 2 * planeSz + halfSz);

        // zero the dummy rows (idx<0 redirect target)
        (void)hipMemsetAsync((char*)pA + (size_t)N * 64, 0, 64, stream);
        (void)hipMemsetAsync((char*)pB + (size_t)N * 64, 0, 64, stream);

        convert_split_kernel<<<2048, 256, 0, stream>>>(
            (const f32x4*)data, pA, pB, (long)N * 8);

        conv_half_kernel<<<1024, 256, 0, stream>>>(
            pA, weights, neigh, outA, gsum, gsq, N, 0);
        conv_half_kernel<<<1024, 256, 0, stream>>>(
            pB, weights, neigh, outB, gsum, gsq, N, 32);

        stats_kernel<<<1, 64, 0, stream>>>(gsum, gsq, gamma, beta,
                                           scale, bias, N);
        norm_split_kernel<<<2048, 256, 0, stream>>>(
            pA ? outA : outA, outB, out, scale, bias, (long)N * 8);
        // (pA?:) keeps -Wunused quiet on some compilers; no-op.
    } else {
        // --- fp32 fallback ---
        conv_fp32_kernel<<<2048, 256, 0, stream>>>(
            data, weights, neigh, out, gsum, gsq, N);
        stats_kernel<<<1, 64, 0, stream>>>(gsum, gsq, gamma, beta,
                                           scale, bias, N);
        norm_kernel<<<2048, 256, 0, stream>>>(
            out, scale, bias, (long)N * (CC / 4));
    }
}

// Round 6
// 982.717 us; speedup vs baseline: 1.2954x; 1.1534x over previous
//
#include <hip/hip_runtime.h>

#define KK 27
#define CC 64
#define EPS 1e-5f

typedef float    f32x4 __attribute__((ext_vector_type(4)));
typedef unsigned u32x4 __attribute__((ext_vector_type(4)));

// ---------------------------------------------------------------------------
// Pack two fp32 -> bf16x2 (round-to-nearest-even)
// ---------------------------------------------------------------------------
__device__ __forceinline__ unsigned pack_bf16x2(float a, float b) {
    unsigned ua = __float_as_uint(a);
    unsigned ub = __float_as_uint(b);
    ua = (ua + 0x7fffu + ((ua >> 16) & 1u)) >> 16;
    ub = (ub + 0x7fffu + ((ub >> 16) & 1u)) >> 16;
    return ua | (ub << 16);
}

// ---------------------------------------------------------------------------
// Kernel 0: fp32 data [N][64] -> packed bf16 [N][64] (128 MB).
// ---------------------------------------------------------------------------
__global__ __launch_bounds__(256, 8) void convert_kernel(
    const f32x4* __restrict__ d4, u32x4* __restrict__ o4, long n_out)
{
    const long stride = (long)gridDim.x * 256;
    for (long i = (long)blockIdx.x * 256 + threadIdx.x; i < n_out; i += stride) {
        f32x4 a = __builtin_nontemporal_load(&d4[2 * i]);
        f32x4 b = __builtin_nontemporal_load(&d4[2 * i + 1]);
        u32x4 o;
        o.x = pack_bf16x2(a.x, a.y);
        o.y = pack_bf16x2(a.z, a.w);
        o.z = pack_bf16x2(b.x, b.y);
        o.w = pack_bf16x2(b.z, b.w);
        o4[i] = o;
    }
}

// ---------------------------------------------------------------------------
// Kernel 1: gather-conv + per-channel partial sums. R3 structure (proven
// 64 VGPR / no spill at 4 waves/EU) but launch_bounds(256,6): VGPR cap 85,
// natural usage 64 -> no squeeze, occupancy 44% -> ~66-75%.
// 8 lanes per row (lane = 8 channels = one u32x4 = 16B), 32 rows/block iter.
// BF16_OUT: write packed-bf16 intermediate (to ws) instead of fp32.
// ---------------------------------------------------------------------------
template <bool BF16_OUT>
__global__ __launch_bounds__(256, 6) void conv_bf16_kernel(
    const u32x4* __restrict__ dbf,      // [N][8] u32x4 rows (packed bf16)
    const float* __restrict__ weights,  // [27][64] fp32
    const int*   __restrict__ neigh,    // [N][27]
    float* __restrict__ outf,           // [N][64] fp32 (if !BF16_OUT)
    u32x4* __restrict__ outb,           // [N][8]  bf16 (if BF16_OUT)
    float* __restrict__ gsum,
    float* __restrict__ gsq,
    int N)
{
    __shared__ float s_w[KK * CC];       // 6912 B
    __shared__ int   s_idx[32 * 28];     // 3584 B
    __shared__ float s_red[256 * 8];     // 8192 B

    const int tid = threadIdx.x;
    for (int i = tid; i < KK * CC / 4; i += 256)
        ((f32x4*)s_w)[i] = ((const f32x4*)weights)[i];

    const int lane = tid & 7;   // channels lane*8 .. lane*8+7
    const int r    = tid >> 3;  // row within block-iteration (0..31)

    float lsum[8], lsq[8];
    #pragma unroll
    for (int j = 0; j < 8; ++j) { lsum[j] = 0.f; lsq[j] = 0.f; }

    const long rows_per_iter = (long)gridDim.x * 32;
    for (long base = (long)blockIdx.x * 32; base < N; base += rows_per_iter) {
        __syncthreads();
        {
            const int nrows = (int)min((long)32, (long)N - base);
            const int tot = nrows * KK;
            for (int i = tid; i < tot; i += 256) {
                const int rr = i / KK;
                const int kk = i - rr * KK;
                s_idx[rr * 28 + kk] =
                    __builtin_nontemporal_load(&neigh[(base + rr) * KK + kk]);
            }
        }
        __syncthreads();

        const long row = base + r;
        if (row < N) {
            float acc[8];
            #pragma unroll
            for (int j = 0; j < 8; ++j) acc[j] = 0.f;

            const int4* nb4 = (const int4*)&s_idx[r * 28];

            auto process = [&](int idx, int k) {
                const unsigned msk = (idx >= 0) ? 0xffffffffu : 0u;
                const long ci = (idx >= 0) ? (long)idx : 0L;
                u32x4 g = dbf[ci * 8 + lane];
                g.x &= msk; g.y &= msk; g.z &= msk; g.w &= msk;
                const f32x4 w0 = *(const f32x4*)&s_w[k * CC + lane * 8];
                const f32x4 w1 = *(const f32x4*)&s_w[k * CC + lane * 8 + 4];
                acc[0] = fmaf(__uint_as_float(g.x << 16),         w0.x, acc[0]);
                acc[1] = fmaf(__uint_as_float(g.x & 0xffff0000u), w0.y, acc[1]);
                acc[2] = fmaf(__uint_as_float(g.y << 16),         w0.z, acc[2]);
                acc[3] = fmaf(__uint_as_float(g.y & 0xffff0000u), w0.w, acc[3]);
                acc[4] = fmaf(__uint_as_float(g.z << 16),         w1.x, acc[4]);
                acc[5] = fmaf(__uint_as_float(g.z & 0xffff0000u), w1.y, acc[5]);
                acc[6] = fmaf(__uint_as_float(g.w << 16),         w1.z, acc[6]);
                acc[7] = fmaf(__uint_as_float(g.w & 0xffff0000u), w1.w, acc[7]);
            };

            #pragma unroll
            for (int kk = 0; kk < 7; ++kk) {
                const int4 q = nb4[kk];
                const int kb = kk * 4;
                process(q.x, kb + 0);
                process(q.y, kb + 1);
                process(q.z, kb + 2);
                if (kb + 3 < KK) process(q.w, kb + 3);
            }

            if (BF16_OUT) {
                u32x4 o;
                o.x = pack_bf16x2(acc[0], acc[1]);
                o.y = pack_bf16x2(acc[2], acc[3]);
                o.z = pack_bf16x2(acc[4], acc[5]);
                o.w = pack_bf16x2(acc[6], acc[7]);
                __builtin_nontemporal_store(o, &outb[row * 8 + lane]);
            } else {
                f32x4 v0 = {acc[0], acc[1], acc[2], acc[3]};
                f32x4 v1 = {acc[4], acc[5], acc[6], acc[7]};
                f32x4* op = (f32x4*)&outf[row * CC + lane * 8];
                __builtin_nontemporal_store(v0, &op[0]);
                __builtin_nontemporal_store(v1, &op[1]);
            }

            #pragma unroll
            for (int j = 0; j < 8; ++j) {
                lsum[j] += acc[j];
                lsq[j]  += acc[j] * acc[j];
            }
        }
    }

    __syncthreads();
    #pragma unroll
    for (int j = 0; j < 8; ++j) s_red[tid * 8 + j] = lsum[j];
    __syncthreads();
    if (tid < CC) {
        const int blk = tid >> 3, off = tid & 7;
        float s = 0.f;
        for (int rr = 0; rr < 32; ++rr) s += s_red[(rr * 8 + blk) * 8 + off];
        atomicAdd(&gsum[tid], s);
    }
    __syncthreads();
    #pragma unroll
    for (int j = 0; j < 8; ++j) s_red[tid * 8 + j] = lsq[j];
    __syncthreads();
    if (tid < CC) {
        const int blk = tid >> 3, off = tid & 7;
        float s = 0.f;
        for (int rr = 0; rr < 32; ++rr) s += s_red[(rr * 8 + blk) * 8 + off];
        atomicAdd(&gsq[tid], s);
    }
}

// ---------------------------------------------------------------------------
// Kernel 2: fold sums into per-channel scale/bias
// ---------------------------------------------------------------------------
__global__ void stats_kernel(const float* __restrict__ gsum,
                             const float* __restrict__ gsq,
                             const float* __restrict__ gamma,
                             const float* __restrict__ beta,
                             float* __restrict__ scale,
                             float* __restrict__ bias,
                             int N)
{
    const int c = threadIdx.x;
    if (c < CC) {
        const float inv_n = 1.0f / (float)N;
        const float mean = gsum[c] * inv_n;
        float var = gsq[c] * inv_n - mean * mean;
        var = fmaxf(var, 0.0f);
        const float s = gamma[c] * rsqrtf(var + EPS);
        scale[c] = s;
        bias[c] = beta[c] - mean * s;
    }
}

// ---------------------------------------------------------------------------
// Kernel 3a: in-place normalize fp32 out (fallback path)
// ---------------------------------------------------------------------------
__global__ __launch_bounds__(256, 8) void norm_kernel(
    float* __restrict__ out,
    const float* __restrict__ scale,
    const float* __restrict__ bias,
    long total4)
{
    const long i0 = (long)blockIdx.x * 256 + threadIdx.x;
    const int cq = (int)(i0 & 15);
    const f32x4 s = reinterpret_cast<const f32x4*>(scale)[cq];
    const f32x4 b = reinterpret_cast<const f32x4*>(bias)[cq];
    f32x4* o4 = reinterpret_cast<f32x4*>(out);
    const long stride = (long)gridDim.x * 256;
    for (long i = i0; i < total4; i += stride) {
        f32x4 v = __builtin_nontemporal_load(&o4[i]);
        v = v * s + b;
        __builtin_nontemporal_store(v, &o4[i]);
    }
}

// ---------------------------------------------------------------------------
// Kernel 3b: normalize from bf16 intermediate -> fp32 d_out.
// ---------------------------------------------------------------------------
__global__ __launch_bounds__(256, 8) void norm_bf16_kernel(
    const u32x4* __restrict__ inb,      // [N][8]
    float* __restrict__ out,            // [N][64]
    const float* __restrict__ scale,
    const float* __restrict__ bias,
    long total8)                        // N * 8
{
    const long i0 = (long)blockIdx.x * 256 + threadIdx.x;
    const int lane = (int)(i0 & 7);
    const f32x4 s0 = reinterpret_cast<const f32x4*>(scale)[lane * 2];
    const f32x4 s1 = reinterpret_cast<const f32x4*>(scale)[lane * 2 + 1];
    const f32x4 b0 = reinterpret_cast<const f32x4*>(bias)[lane * 2];
    const f32x4 b1 = reinterpret_cast<const f32x4*>(bias)[lane * 2 + 1];
    const long stride = (long)gridDim.x * 256;   // multiple of 8
    for (long i = i0; i < total8; i += stride) {
        u32x4 g = __builtin_nontemporal_load(&inb[i]);
        f32x4 v0, v1;
        v0.x = __uint_as_float(g.x << 16);
        v0.y = __uint_as_float(g.x & 0xffff0000u);
        v0.z = __uint_as_float(g.y << 16);
        v0.w = __uint_as_float(g.y & 0xffff0000u);
        v1.x = __uint_as_float(g.z << 16);
        v1.y = __uint_as_float(g.z & 0xffff0000u);
        v1.z = __uint_as_float(g.w << 16);
        v1.w = __uint_as_float(g.w & 0xffff0000u);
        v0 = v0 * s0 + b0;
        v1 = v1 * s1 + b1;
        f32x4* op = (f32x4*)&out[i * 8];
        __builtin_nontemporal_store(v0, &op[0]);
        __builtin_nontemporal_store(v1, &op[1]);
    }
}

// ---------------------------------------------------------------------------
// Fallback fp32 conv (only if ws too small for the bf16 data copy).
// ---------------------------------------------------------------------------
__global__ __launch_bounds__(256, 4) void conv_fp32_kernel(
    const float* __restrict__ data,
    const float* __restrict__ weights,
    const int*   __restrict__ neigh,
    float* __restrict__ out,
    float* __restrict__ gsum,
    float* __restrict__ gsq,
    int N)
{
    __shared__ f32x4 s_w[KK * 16];
    __shared__ f32x4 s_red[256];

    const int tid = threadIdx.x;
    for (int i = tid; i < KK * 16; i += 256)
        s_w[i] = reinterpret_cast<const f32x4*>(weights)[i];
    __syncthreads();

    const int cq = tid & 15;
    const int rg = tid >> 4;
    const f32x4* data4 = reinterpret_cast<const f32x4*>(data);
    f32x4* out4 = reinterpret_cast<f32x4*>(out);

    f32x4 lsum = {0.f, 0.f, 0.f, 0.f};
    f32x4 lsq  = {0.f, 0.f, 0.f, 0.f};

    const long rows_per_iter = (long)gridDim.x * 16;
    for (long base = (long)blockIdx.x * 16; base < N; base += rows_per_iter) {
        const long row = base + rg;
        if (row < N) {
            f32x4 acc = {0.f, 0.f, 0.f, 0.f};
            const int* nb = neigh + row * KK;
            #pragma unroll
            for (int k = 0; k < KK; ++k) {
                const int idx = nb[k];
                if (idx >= 0) {
                    const f32x4 g = data4[(long)idx * 16 + cq];
                    const f32x4 w = s_w[k * 16 + cq];
                    acc += g * w;
                }
            }
            out4[row * 16 + cq] = acc;
            lsum += acc;
            lsq  += acc * acc;
        }
    }

    s_red[tid] = lsum;
    __syncthreads();
    if (rg == 0) {
        f32x4 t = s_red[cq];
        #pragma unroll
        for (int r = 1; r < 16; ++r) t += s_red[r * 16 + cq];
        atomicAdd(&gsum[cq * 4 + 0], t.x);
        atomicAdd(&gsum[cq * 4 + 1], t.y);
        atomicAdd(&gsum[cq * 4 + 2], t.z);
        atomicAdd(&gsum[cq * 4 + 3], t.w);
    }
    __syncthreads();
    s_red[tid] = lsq;
    __syncthreads();
    if (rg == 0) {
        f32x4 t = s_red[cq];
        #pragma unroll
        for (int r = 1; r < 16; ++r) t += s_red[r * 16 + cq];
        atomicAdd(&gsq[cq * 4 + 0], t.x);
        atomicAdd(&gsq[cq * 4 + 1], t.y);
        atomicAdd(&gsq[cq * 4 + 2], t.z);
        atomicAdd(&gsq[cq * 4 + 3], t.w);
    }
}

extern "C" void kernel_launch(void* const* d_in, const int* in_sizes, int n_in,
                              void* d_out, int out_size, void* d_ws, size_t ws_size,
                              hipStream_t stream)
{
    const float* data    = (const float*)d_in[0];
    const float* weights = (const float*)d_in[1];
    const float* gamma   = (const float*)d_in[2];
    const float* beta    = (const float*)d_in[3];
    const int*   neigh   = (const int*)d_in[4];
    float* out = (float*)d_out;
    const int N = in_sizes[0] / CC;     // 1,000,000

    float* gsum  = (float*)d_ws;        // [64]
    float* gsq   = gsum + CC;           // [64]
    float* scale = gsq + CC;            // [64]
    float* bias  = scale + CC;          // [64]

    (void)hipMemsetAsync(d_ws, 0, 2 * CC * sizeof(float), stream);

    const size_t bf16_bytes = (size_t)N * CC * 2;   // 128 MB
    const size_t off1 = 1024;                        // data bf16 copy
    const size_t off2 = off1 + bf16_bytes;           // conv bf16 intermediate

    if (ws_size >= off1 + bf16_bytes) {
        u32x4* dbf = (u32x4*)((char*)d_ws + off1);
        const long n_out = (long)N * CC / 8;
        convert_kernel<<<2048, 256, 0, stream>>>(
            (const f32x4*)data, dbf, n_out);

        const bool bf16_out = (ws_size >= off2 + bf16_bytes);
        if (bf16_out) {
            u32x4* cbf = (u32x4*)((char*)d_ws + off2);
            conv_bf16_kernel<true><<<1536, 256, 0, stream>>>(
                dbf, weights, neigh, nullptr, cbf, gsum, gsq, N);
            stats_kernel<<<1, 64, 0, stream>>>(gsum, gsq, gamma, beta,
                                               scale, bias, N);
            norm_bf16_kernel<<<2048, 256, 0, stream>>>(
                cbf, out, scale, bias, (long)N * 8);
        } else {
            conv_bf16_kernel<false><<<1536, 256, 0, stream>>>(
                dbf, weights, neigh, out, nullptr, gsum, gsq, N);
            stats_kernel<<<1, 64, 0, stream>>>(gsum, gsq, gamma, beta,
                                               scale, bias, N);
            norm_kernel<<<2048, 256, 0, stream>>>(
                out, scale, bias, (long)N * (CC / 4));
        }
    } else {
        conv_fp32_kernel<<<2048, 256, 0, stream>>>(
            data, weights, neigh, out, gsum, gsq, N);
        stats_kernel<<<1, 64, 0, stream>>>(gsum, gsq, gamma, beta,
                                           scale, bias, N);
        norm_kernel<<<2048, 256, 0, stream>>>(
            out, scale, bias, (long)N * (CC / 4));
    }
}

// Round 7
// 687.462 us; speedup vs baseline: 1.8518x; 1.4295x over previous
//
#include <hip/hip_runtime.h>

#define KK 27
#define CC 64
#define EPS 1e-5f

typedef float    f32x4 __attribute__((ext_vector_type(4)));
typedef unsigned u32x4 __attribute__((ext_vector_type(4)));

// ---------------------------------------------------------------------------
// Pack two fp32 -> bf16x2 (round-to-nearest-even)
// ---------------------------------------------------------------------------
__device__ __forceinline__ unsigned pack_bf16x2(float a, float b) {
    unsigned ua = __float_as_uint(a);
    unsigned ub = __float_as_uint(b);
    ua = (ua + 0x7fffu + ((ua >> 16) & 1u)) >> 16;
    ub = (ub + 0x7fffu + ((ub >> 16) & 1u)) >> 16;
    return ua | (ub << 16);
}

// ---------------------------------------------------------------------------
// Kernel 0: fp32 data [N][64] -> packed bf16 [N][64] (128 MB).
// ---------------------------------------------------------------------------
__global__ __launch_bounds__(256, 8) void convert_kernel(
    const f32x4* __restrict__ d4, u32x4* __restrict__ o4, long n_out)
{
    const long stride = (long)gridDim.x * 256;
    for (long i = (long)blockIdx.x * 256 + threadIdx.x; i < n_out; i += stride) {
        f32x4 a = __builtin_nontemporal_load(&d4[2 * i]);
        f32x4 b = __builtin_nontemporal_load(&d4[2 * i + 1]);
        u32x4 o;
        o.x = pack_bf16x2(a.x, a.y);
        o.y = pack_bf16x2(a.z, a.w);
        o.z = pack_bf16x2(b.x, b.y);
        o.w = pack_bf16x2(b.z, b.w);
        o4[i] = o;
    }
}

// ---------------------------------------------------------------------------
// Kernel 1: gather-conv + per-channel partial sums.
// EXACT R3 configuration (launch_bounds(256,4): natural VGPR 64, no squeeze,
// no spill — bounds 6/8 both squeezed VGPR and spilled, measured R4/R6).
// Conv is line-request-bound (~50 G lines/s fabric ceiling): 27M gathers
// of one 128B line each -> ~540us floor. Do not trade for occupancy.
// BF16_OUT: write packed-bf16 intermediate (halves conv write + norm read).
// ---------------------------------------------------------------------------
template <bool BF16_OUT>
__global__ __launch_bounds__(256, 4) void conv_bf16_kernel(
    const u32x4* __restrict__ dbf,      // [N][8] u32x4 rows (packed bf16)
    const float* __restrict__ weights,  // [27][64] fp32
    const int*   __restrict__ neigh,    // [N][27]
    float* __restrict__ outf,           // [N][64] fp32 (if !BF16_OUT)
    u32x4* __restrict__ outb,           // [N][8]  bf16 (if BF16_OUT)
    float* __restrict__ gsum,
    float* __restrict__ gsq,
    int N)
{
    __shared__ float s_w[KK * CC];       // 6912 B
    __shared__ int   s_idx[32 * 28];     // 3584 B
    __shared__ float s_red[256 * 8];     // 8192 B

    const int tid = threadIdx.x;
    for (int i = tid; i < KK * CC / 4; i += 256)
        ((f32x4*)s_w)[i] = ((const f32x4*)weights)[i];

    const int lane = tid & 7;   // channels lane*8 .. lane*8+7
    const int r    = tid >> 3;  // row within block-iteration (0..31)

    float lsum[8], lsq[8];
    #pragma unroll
    for (int j = 0; j < 8; ++j) { lsum[j] = 0.f; lsq[j] = 0.f; }

    const long rows_per_iter = (long)gridDim.x * 32;
    for (long base = (long)blockIdx.x * 32; base < N; base += rows_per_iter) {
        __syncthreads();
        {
            const int nrows = (int)min((long)32, (long)N - base);
            const int tot = nrows * KK;
            for (int i = tid; i < tot; i += 256) {
                const int rr = i / KK;
                const int kk = i - rr * KK;
                s_idx[rr * 28 + kk] =
                    __builtin_nontemporal_load(&neigh[(base + rr) * KK + kk]);
            }
        }
        __syncthreads();

        const long row = base + r;
        if (row < N) {
            float acc[8];
            #pragma unroll
            for (int j = 0; j < 8; ++j) acc[j] = 0.f;

            const int4* nb4 = (const int4*)&s_idx[r * 28];

            auto process = [&](int idx, int k) {
                const unsigned msk = (idx >= 0) ? 0xffffffffu : 0u;
                const long ci = (idx >= 0) ? (long)idx : 0L;
                u32x4 g = dbf[ci * 8 + lane];
                g.x &= msk; g.y &= msk; g.z &= msk; g.w &= msk;
                const f32x4 w0 = *(const f32x4*)&s_w[k * CC + lane * 8];
                const f32x4 w1 = *(const f32x4*)&s_w[k * CC + lane * 8 + 4];
                acc[0] = fmaf(__uint_as_float(g.x << 16),         w0.x, acc[0]);
                acc[1] = fmaf(__uint_as_float(g.x & 0xffff0000u), w0.y, acc[1]);
                acc[2] = fmaf(__uint_as_float(g.y << 16),         w0.z, acc[2]);
                acc[3] = fmaf(__uint_as_float(g.y & 0xffff0000u), w0.w, acc[3]);
                acc[4] = fmaf(__uint_as_float(g.z << 16),         w1.x, acc[4]);
                acc[5] = fmaf(__uint_as_float(g.z & 0xffff0000u), w1.y, acc[5]);
                acc[6] = fmaf(__uint_as_float(g.w << 16),         w1.z, acc[6]);
                acc[7] = fmaf(__uint_as_float(g.w & 0xffff0000u), w1.w, acc[7]);
            };

            #pragma unroll
            for (int kk = 0; kk < 7; ++kk) {
                const int4 q = nb4[kk];
                const int kb = kk * 4;
                process(q.x, kb + 0);
                process(q.y, kb + 1);
                process(q.z, kb + 2);
                if (kb + 3 < KK) process(q.w, kb + 3);
            }

            if (BF16_OUT) {
                u32x4 o;
                o.x = pack_bf16x2(acc[0], acc[1]);
                o.y = pack_bf16x2(acc[2], acc[3]);
                o.z = pack_bf16x2(acc[4], acc[5]);
                o.w = pack_bf16x2(acc[6], acc[7]);
                __builtin_nontemporal_store(o, &outb[row * 8 + lane]);
            } else {
                f32x4 v0 = {acc[0], acc[1], acc[2], acc[3]};
                f32x4 v1 = {acc[4], acc[5], acc[6], acc[7]};
                f32x4* op = (f32x4*)&outf[row * CC + lane * 8];
                __builtin_nontemporal_store(v0, &op[0]);
                __builtin_nontemporal_store(v1, &op[1]);
            }

            #pragma unroll
            for (int j = 0; j < 8; ++j) {
                lsum[j] += acc[j];
                lsq[j]  += acc[j] * acc[j];
            }
        }
    }

    __syncthreads();
    #pragma unroll
    for (int j = 0; j < 8; ++j) s_red[tid * 8 + j] = lsum[j];
    __syncthreads();
    if (tid < CC) {
        const int blk = tid >> 3, off = tid & 7;
        float s = 0.f;
        for (int rr = 0; rr < 32; ++rr) s += s_red[(rr * 8 + blk) * 8 + off];
        atomicAdd(&gsum[tid], s);
    }
    __syncthreads();
    #pragma unroll
    for (int j = 0; j < 8; ++j) s_red[tid * 8 + j] = lsq[j];
    __syncthreads();
    if (tid < CC) {
        const int blk = tid >> 3, off = tid & 7;
        float s = 0.f;
        for (int rr = 0; rr < 32; ++rr) s += s_red[(rr * 8 + blk) * 8 + off];
        atomicAdd(&gsq[tid], s);
    }
}

// ---------------------------------------------------------------------------
// Kernel 2: fold sums into per-channel scale/bias
// ---------------------------------------------------------------------------
__global__ void stats_kernel(const float* __restrict__ gsum,
                             const float* __restrict__ gsq,
                             const float* __restrict__ gamma,
                             const float* __restrict__ beta,
                             float* __restrict__ scale,
                             float* __restrict__ bias,
                             int N)
{
    const int c = threadIdx.x;
    if (c < CC) {
        const float inv_n = 1.0f / (float)N;
        const float mean = gsum[c] * inv_n;
        float var = gsq[c] * inv_n - mean * mean;
        var = fmaxf(var, 0.0f);
        const float s = gamma[c] * rsqrtf(var + EPS);
        scale[c] = s;
        bias[c] = beta[c] - mean * s;
    }
}

// ---------------------------------------------------------------------------
// Kernel 3a: in-place normalize fp32 out (fallback path)
// ---------------------------------------------------------------------------
__global__ __launch_bounds__(256, 8) void norm_kernel(
    float* __restrict__ out,
    const float* __restrict__ scale,
    const float* __restrict__ bias,
    long total4)
{
    const long i0 = (long)blockIdx.x * 256 + threadIdx.x;
    const int cq = (int)(i0 & 15);
    const f32x4 s = reinterpret_cast<const f32x4*>(scale)[cq];
    const f32x4 b = reinterpret_cast<const f32x4*>(bias)[cq];
    f32x4* o4 = reinterpret_cast<f32x4*>(out);
    const long stride = (long)gridDim.x * 256;
    for (long i = i0; i < total4; i += stride) {
        f32x4 v = __builtin_nontemporal_load(&o4[i]);
        v = v * s + b;
        __builtin_nontemporal_store(v, &o4[i]);
    }
}

// ---------------------------------------------------------------------------
// Kernel 3b: normalize from bf16 intermediate -> fp32 d_out.
// ---------------------------------------------------------------------------
__global__ __launch_bounds__(256, 8) void norm_bf16_kernel(
    const u32x4* __restrict__ inb,      // [N][8]
    float* __restrict__ out,            // [N][64]
    const float* __restrict__ scale,
    const float* __restrict__ bias,
    long total8)                        // N * 8
{
    const long i0 = (long)blockIdx.x * 256 + threadIdx.x;
    const int lane = (int)(i0 & 7);
    const f32x4 s0 = reinterpret_cast<const f32x4*>(scale)[lane * 2];
    const f32x4 s1 = reinterpret_cast<const f32x4*>(scale)[lane * 2 + 1];
    const f32x4 b0 = reinterpret_cast<const f32x4*>(bias)[lane * 2];
    const f32x4 b1 = reinterpret_cast<const f32x4*>(bias)[lane * 2 + 1];
    const long stride = (long)gridDim.x * 256;   // multiple of 8
    for (long i = i0; i < total8; i += stride) {
        u32x4 g = __builtin_nontemporal_load(&inb[i]);
        f32x4 v0, v1;
        v0.x = __uint_as_float(g.x << 16);
        v0.y = __uint_as_float(g.x & 0xffff0000u);
        v0.z = __uint_as_float(g.y << 16);
        v0.w = __uint_as_float(g.y & 0xffff0000u);
        v1.x = __uint_as_float(g.z << 16);
        v1.y = __uint_as_float(g.z & 0xffff0000u);
        v1.z = __uint_as_float(g.w << 16);
        v1.w = __uint_as_float(g.w & 0xffff0000u);
        v0 = v0 * s0 + b0;
        v1 = v1 * s1 + b1;
        f32x4* op = (f32x4*)&out[i * 8];
        __builtin_nontemporal_store(v0, &op[0]);
        __builtin_nontemporal_store(v1, &op[1]);
    }
}

// ---------------------------------------------------------------------------
// Fallback fp32 conv (only if ws too small for the bf16 data copy).
// ---------------------------------------------------------------------------
__global__ __launch_bounds__(256, 4) void conv_fp32_kernel(
    const float* __restrict__ data,
    const float* __restrict__ weights,
    const int*   __restrict__ neigh,
    float* __restrict__ out,
    float* __restrict__ gsum,
    float* __restrict__ gsq,
    int N)
{
    __shared__ f32x4 s_w[KK * 16];
    __shared__ f32x4 s_red[256];

    const int tid = threadIdx.x;
    for (int i = tid; i < KK * 16; i += 256)
        s_w[i] = reinterpret_cast<const f32x4*>(weights)[i];
    __syncthreads();

    const int cq = tid & 15;
    const int rg = tid >> 4;
    const f32x4* data4 = reinterpret_cast<const f32x4*>(data);
    f32x4* out4 = reinterpret_cast<f32x4*>(out);

    f32x4 lsum = {0.f, 0.f, 0.f, 0.f};
    f32x4 lsq  = {0.f, 0.f, 0.f, 0.f};

    const long rows_per_iter = (long)gridDim.x * 16;
    for (long base = (long)blockIdx.x * 16; base < N; base += rows_per_iter) {
        const long row = base + rg;
        if (row < N) {
            f32x4 acc = {0.f, 0.f, 0.f, 0.f};
            const int* nb = neigh + row * KK;
            #pragma unroll
            for (int k = 0; k < KK; ++k) {
                const int idx = nb[k];
                if (idx >= 0) {
                    const f32x4 g = data4[(long)idx * 16 + cq];
                    const f32x4 w = s_w[k * 16 + cq];
                    acc += g * w;
                }
            }
            out4[row * 16 + cq] = acc;
            lsum += acc;
            lsq  += acc * acc;
        }
    }

    s_red[tid] = lsum;
    __syncthreads();
    if (rg == 0) {
        f32x4 t = s_red[cq];
        #pragma unroll
        for (int r = 1; r < 16; ++r) t += s_red[r * 16 + cq];
        atomicAdd(&gsum[cq * 4 + 0], t.x);
        atomicAdd(&gsum[cq * 4 + 1], t.y);
        atomicAdd(&gsum[cq * 4 + 2], t.z);
        atomicAdd(&gsum[cq * 4 + 3], t.w);
    }
    __syncthreads();
    s_red[tid] = lsq;
    __syncthreads();
    if (rg == 0) {
        f32x4 t = s_red[cq];
        #pragma unroll
        for (int r = 1; r < 16; ++r) t += s_red[r * 16 + cq];
        atomicAdd(&gsq[cq * 4 + 0], t.x);
        atomicAdd(&gsq[cq * 4 + 1], t.y);
        atomicAdd(&gsq[cq * 4 + 2], t.z);
        atomicAdd(&gsq[cq * 4 + 3], t.w);
    }
}

extern "C" void kernel_launch(void* const* d_in, const int* in_sizes, int n_in,
                              void* d_out, int out_size, void* d_ws, size_t ws_size,
                              hipStream_t stream)
{
    const float* data    = (const float*)d_in[0];
    const float* weights = (const float*)d_in[1];
    const float* gamma   = (const float*)d_in[2];
    const float* beta    = (const float*)d_in[3];
    const int*   neigh   = (const int*)d_in[4];
    float* out = (float*)d_out;
    const int N = in_sizes[0] / CC;     // 1,000,000

    float* gsum  = (float*)d_ws;        // [64]
    float* gsq   = gsum + CC;           // [64]
    float* scale = gsq + CC;            // [64]
    float* bias  = scale + CC;          // [64]

    (void)hipMemsetAsync(d_ws, 0, 2 * CC * sizeof(float), stream);

    const size_t bf16_bytes = (size_t)N * CC * 2;   // 128 MB
    const size_t off1 = 1024;                        // data bf16 copy
    const size_t off2 = off1 + bf16_bytes;           // conv bf16 intermediate

    if (ws_size >= off1 + bf16_bytes) {
        u32x4* dbf = (u32x4*)((char*)d_ws + off1);
        const long n_out = (long)N * CC / 8;
        convert_kernel<<<2048, 256, 0, stream>>>(
            (const f32x4*)data, dbf, n_out);

        const bool bf16_out = (ws_size >= off2 + bf16_bytes);
        if (bf16_out) {
            u32x4* cbf = (u32x4*)((char*)d_ws + off2);
            conv_bf16_kernel<true><<<2048, 256, 0, stream>>>(
                dbf, weights, neigh, nullptr, cbf, gsum, gsq, N);
            stats_kernel<<<1, 64, 0, stream>>>(gsum, gsq, gamma, beta,
                                               scale, bias, N);
            norm_bf16_kernel<<<2048, 256, 0, stream>>>(
                cbf, out, scale, bias, (long)N * 8);
        } else {
            conv_bf16_kernel<false><<<2048, 256, 0, stream>>>(
                dbf, weights, neigh, out, nullptr, gsum, gsq, N);
            stats_kernel<<<1, 64, 0, stream>>>(gsum, gsq, gamma, beta,
                                               scale, bias, N);
            norm_kernel<<<2048, 256, 0, stream>>>(
                out, scale, bias, (long)N * (CC / 4));
        }
    } else {
        conv_fp32_kernel<<<2048, 256, 0, stream>>>(
            data, weights, neigh, out, gsum, gsq, N);
        stats_kernel<<<1, 64, 0, stream>>>(gsum, gsq, gamma, beta,
                                           scale, bias, N);
        norm_kernel<<<2048, 256, 0, stream>>>(
            out, scale, bias, (long)N * (CC / 4));
    }
}